// Round 13
// baseline (485.167 us; speedup 1.0000x reference)
//
#include <hip/hip_runtime.h>

#define NG 8000
#define NHALF 4000
#define TS 1440
#define NOUT 32
#define LENFT 72
#define DTC (1.0f/24.0f)
#define NEARZEROC 1e-5f

// gfx950 hardware transcendentals (base-2). Pure ops -> non-volatile asm (CSE ok).
__device__ __forceinline__ float fexp2(float x) {
  float r; asm("v_exp_f32 %0, %1" : "=v"(r) : "v"(x)); return r;
}
__device__ __forceinline__ float flog2(float x) {
  float r; asm("v_log_f32 %0, %1" : "=v"(r) : "v"(x)); return r;
}

typedef const void __attribute__((address_space(1))) gas_void;
typedef void __attribute__((address_space(3)))       las_void;

// ---------------------------------------------------------------------------
// Kernel 1: per-cell constants + normalized routing weights
// ---------------------------------------------------------------------------
__global__ __launch_bounds__(256) void precompute_kernel(
    const float* __restrict__ p1, const float* __restrict__ p2,
    const float* __restrict__ ac_all,
    float* __restrict__ Cst,   // 16 * NG floats (SoA)
    float* __restrict__ W)     // LENFT * NG floats (k-major)
{
  int n = blockIdx.x * 256 + threadIdx.x;
  if (n >= NG) return;
  const float* r = p1 + n * 19;
  float BETA   = 1.0f   + r[0]  * 5.0f;
  float FC     = 50.0f  + r[1]  * 950.0f;
  float K0     = 0.05f  + r[2]  * 0.85f;
  float K1     = 0.01f  + r[3]  * 0.49f;
  float K2     = 0.001f + r[4]  * 0.199f;
  float LP     = 0.2f   + r[5]  * 0.8f;
  float PERC   =          r[6]  * 10.0f;
  float UZL    =          r[7]  * 100.0f;
  float TT     = -2.5f  + r[8]  * 5.0f;
  float CFMAX  = 0.5f   + r[9]  * 9.5f;
  float CFR    =          r[10] * 0.1f;
  float CWH    =          r[11] * 0.2f;
  float BETAET = 0.3f   + r[12] * 4.7f;
  float Cpar   =          r[13];
  float RT     =          r[14] * 20.0f;
  float AC     =          r[15] * 2500.0f;
  float F0     = 120.0f + r[16] * 2760.0f;
  float FMIN   =          r[17];
  float ALPHA  = 0.5f   + r[18] * 4.5f;

  float ac  = ac_all[n];
  float fmx = DTC * F0 * (FMIN + (1.0f - FMIN) * expf(-powf(ac / (AC + 1.0f), 1.0f / ALPHA)));

  Cst[ 0*NG+n] = TT;            Cst[ 1*NG+n] = CFMAX * DTC;
  Cst[ 2*NG+n] = CFR*CFMAX*DTC; Cst[ 3*NG+n] = CWH;
  Cst[ 4*NG+n] = fmx;           Cst[ 5*NG+n] = 1.0f / FC;
  Cst[ 6*NG+n] = BETA;          Cst[ 7*NG+n] = FC;
  Cst[ 8*NG+n] = Cpar;          Cst[ 9*NG+n] = 1.0f / (LP * FC);
  Cst[10*NG+n] = BETAET;        Cst[11*NG+n] = PERC * DTC;
  Cst[12*NG+n] = K0 * DTC;      Cst[13*NG+n] = UZL;
  Cst[14*NG+n] = K1 * DTC;      Cst[15*NG+n] = K2 * DTC;

  // routing weights (gamma kernel), normalized
  float a   = fmaxf(p2[n*3+0] * 5.0f,  0.01f);
  float b   = fmaxf(p2[n*3+1] * 12.0f, 0.01f);
  float lag = p2[n*3+2] * 48.0f + RT;
  float am1 = a - 1.0f, invb = 1.0f / b;
  float sum = 0.0f;
  for (int k = 0; k < LENFT; k++) {
    float s  = (k + 0.5f) - lag;
    float sm = fmaxf(s, 1e-6f);
    float wv = (s > 0.0f) ? expf(am1 * logf(sm) - sm * invb) : 0.0f;
    sum += wv;
  }
  float inv = 1.0f / (sum + 1e-8f);
  for (int k = 0; k < LENFT; k++) {
    float s  = (k + 0.5f) - lag;
    float sm = fmaxf(s, 1e-6f);
    float wv = (s > 0.0f) ? expf(am1 * logf(sm) - sm * invb) : 0.0f;
    W[k*NG + n] = wv * inv;
  }
}

// ---------------------------------------------------------------------------
// Kernel 2: sequential HBV scan — ILP-2, chains textually interleaved.
// r8's ILP-2 failed (815 cyc/pair = 2x407, zero overlap) because the two
// hbv_step calls were sequential + loads were JIT. This version interleaves
// the two cells' ops statement-by-statement and keeps the proven r11
// register-staging pattern (depth-4 double buffer per cell).
// Exact trims (bit-identical to ref, proofs in journal):
//  - melt/refr mutually exclusive -> transfer = med3(k*dT, -MW, SP)
//  - cap outer min redundant (C,u<=1, RN monotone)
//  - et min redundant under the max(.,1e-5) clamp
// ---------------------------------------------------------------------------
struct HbvConst {
  float TT, CFMAXDT, CFRDT, CWH, FMX, IFC, BETA, FC, C, ILF, BETAET,
        PERCDT, K0DT, UZL, K1DT, K2DT;
};

__device__ __forceinline__ void load_const(const float* __restrict__ Cst,
                                           int n, HbvConst& c) {
  c.TT    =Cst[ 0*NG+n]; c.CFMAXDT=Cst[ 1*NG+n]; c.CFRDT =Cst[ 2*NG+n];
  c.CWH   =Cst[ 3*NG+n]; c.FMX    =Cst[ 4*NG+n]; c.IFC   =Cst[ 5*NG+n];
  c.BETA  =Cst[ 6*NG+n]; c.FC     =Cst[ 7*NG+n]; c.C     =Cst[ 8*NG+n];
  c.ILF   =Cst[ 9*NG+n]; c.BETAET =Cst[10*NG+n]; c.PERCDT=Cst[11*NG+n];
  c.K0DT  =Cst[12*NG+n]; c.UZL    =Cst[13*NG+n]; c.K1DT  =Cst[14*NG+n];
  c.K2DT  =Cst[15*NG+n];
}

__device__ __forceinline__ void hbv_step2(
    const float3 v0, const float3 v1,
    const HbvConst& c0, const HbvConst& c1,
    float& SP0, float& MW0, float& SM0, float& SUZ0, float& SLZ0,
    float& SP1, float& MW1, float& SM1, float& SUZ1, float& SLZ1,
    float& out0, float& out1)
{
  bool  w0    = v0.y >= c0.TT;            bool  w1    = v1.y >= c1.TT;
  float dT0   = v0.y - c0.TT;             float dT1   = v1.y - c1.TT;
  float rain0 = w0 ? v0.x : 0.0f;         float rain1 = w1 ? v1.x : 0.0f;
  SP0 += v0.x - rain0;                    SP1 += v1.x - rain1;
  float k0    = w0 ? c0.CFMAXDT : c0.CFRDT;
  float k1    = w1 ? c1.CFMAXDT : c1.CFRDT;
  float tr0   = __builtin_amdgcn_fmed3f(k0 * dT0, -MW0, SP0);
  float tr1   = __builtin_amdgcn_fmed3f(k1 * dT1, -MW1, SP1);
  MW0 += tr0; SP0 -= tr0;                 MW1 += tr1; SP1 -= tr1;
  float tos0  = fmaxf(MW0 - c0.CWH * SP0, 0.0f);
  float tos1  = fmaxf(MW1 - c1.CWH * SP1, 0.0f);
  MW0 -= tos0;                            MW1 -= tos1;
  float win0  = rain0 + tos0;             float win1  = rain1 + tos1;
  float inf0  = fminf(win0, c0.FMX);      float inf1  = fminf(win1, c1.FMX);
  float qie0  = win0 - inf0;              float qie1  = win1 - inf1;
  float l0    = flog2(SM0 * c0.IFC);      float l1    = flog2(SM1 * c1.IFC);
  float sw0   = fminf(fexp2(c0.BETA * l0), 1.0f);
  float sw1   = fminf(fexp2(c1.BETA * l1), 1.0f);
  float rech0 = inf0 * sw0;               float rech1 = inf1 * sw1;
  SM0 += inf0 - rech0;                    SM1 += inf1 - rech1;
  float exc0  = fmaxf(SM0 - c0.FC, 0.0f); float exc1  = fmaxf(SM1 - c1.FC, 0.0f);
  SM0 -= exc0;                            SM1 -= exc1;
  float m0    = SM0 * c0.IFC;             float m1    = SM1 * c1.IFC;
  float u0    = fmaxf(1.0f - m0, 0.0f);   float u1    = fmaxf(1.0f - m1, 0.0f);
  float cap0  = c0.C * SLZ0 * u0;         float cap1  = c1.C * SLZ1 * u1;
  SM0 += cap0; SLZ0 -= cap0;              SM1 += cap1; SLZ1 -= cap1;
  float g0    = flog2(SM0 * c0.ILF);      float g1    = flog2(SM1 * c1.ILF);
  float ef0   = fminf(fexp2(c0.BETAET * g0), 1.0f);
  float ef1   = fminf(fexp2(c1.BETAET * g1), 1.0f);
  SM0 = fmaxf(SM0 - v0.z * ef0, NEARZEROC);
  SM1 = fmaxf(SM1 - v1.z * ef1, NEARZEROC);
  SUZ0 += rech0 + exc0;                   SUZ1 += rech1 + exc1;
  float p0    = fminf(SUZ0, c0.PERCDT);   float p1    = fminf(SUZ1, c1.PERCDT);
  SUZ0 -= p0;                             SUZ1 -= p1;
  float qa0   = c0.K0DT * fmaxf(SUZ0 - c0.UZL, 0.0f);
  float qa1   = c1.K0DT * fmaxf(SUZ1 - c1.UZL, 0.0f);
  SUZ0 -= qa0;                            SUZ1 -= qa1;
  float qb0   = c0.K1DT * SUZ0;           float qb1   = c1.K1DT * SUZ1;
  SUZ0 -= qb0;                            SUZ1 -= qb1;
  SLZ0 += p0;                             SLZ1 += p1;
  float qc0   = c0.K2DT * SLZ0;           float qc1   = c1.K2DT * SLZ1;
  SLZ0 -= qc0;                            SLZ1 -= qc1;
  out0 = qie0 + qa0 + qb0 + qc0;          out1 = qie1 + qa1 + qb1 + qc1;
}

#define LD3(p, t) (*reinterpret_cast<const float3*>((p) + (size_t)(t) * (NG * 3)))

__global__ __launch_bounds__(64, 1) void scan_kernel(
    const float* __restrict__ x, const float* __restrict__ Cst,
    float* __restrict__ Q)
{
  int n0 = blockIdx.x * 64 + threadIdx.x;
  if (n0 >= NHALF) return;
  int n1 = n0 + NHALF;

  HbvConst c0, c1;
  load_const(Cst, n0, c0);
  load_const(Cst, n1, c1);

  float SP0=1e-3f, MW0=1e-3f, SM0=1e-3f, SUZ0=1e-3f, SLZ0=1e-3f;
  float SP1=1e-3f, MW1=1e-3f, SM1=1e-3f, SUZ1=1e-3f, SLZ1=1e-3f;

  const float* xp0 = x + (size_t)n0 * 3;
  const float* xp1 = x + (size_t)n1 * 3;
  float* Qp0 = Q + n0;
  float* Qp1 = Q + n1;

  float3 a0[4], a1[4], b0[4], b1[4];
  #pragma unroll
  for (int i = 0; i < 4; i++) { a0[i] = LD3(xp0, i); a1[i] = LD3(xp1, i); }

  for (int tb = 0; tb < TS; tb += 8) {
    #pragma unroll
    for (int i = 0; i < 4; i++) {       // prefetch next 4 steps
      b0[i] = LD3(xp0, tb + 4 + i); b1[i] = LD3(xp1, tb + 4 + i);
    }
    #pragma unroll
    for (int i = 0; i < 4; i++) {
      float o0, o1;
      hbv_step2(a0[i], a1[i], c0, c1,
                SP0, MW0, SM0, SUZ0, SLZ0,
                SP1, MW1, SM1, SUZ1, SLZ1, o0, o1);
      Qp0[(size_t)(tb + i) * NG] = o0;
      Qp1[(size_t)(tb + i) * NG] = o1;
    }
    if (tb + 8 < TS) {
      #pragma unroll
      for (int i = 0; i < 4; i++) {
        a0[i] = LD3(xp0, tb + 8 + i); a1[i] = LD3(xp1, tb + 8 + i);
      }
    }
    #pragma unroll
    for (int i = 0; i < 4; i++) {
      float o0, o1;
      hbv_step2(b0[i], b1[i], c0, c1,
                SP0, MW0, SM0, SUZ0, SLZ0,
                SP1, MW1, SM1, SUZ1, SLZ1, o0, o1);
      Qp0[(size_t)(tb + 4 + i) * NG] = o0;
      Qp1[(size_t)(tb + 4 + i) * NG] = o1;
    }
  }
}

// ---------------------------------------------------------------------------
// Kernel 3: fused routing FIR (72 taps) + partial einsum — UNCHANGED (r12).
// gll staging, async stage(sub+1) under einsum, bijective XCD chunk swizzle.
// ---------------------------------------------------------------------------
#define TTILE 48
#define NTILES_T 30          // 1440 / 48
#define NSPLIT 25
#define SUBS 5               // subtiles per split (25*5*64 = 8000)
#define QROWS (TTILE + 71)   // 119
#define NWG (NTILES_T * NSPLIT)  // 750

__global__ __launch_bounds__(256, 2) void route_kernel(
    const float* __restrict__ Q, const float* __restrict__ W,
    const float* __restrict__ topo, const float* __restrict__ areas,
    float* __restrict__ Par)   // [NSPLIT][TS][NOUT]
{
  __shared__ float Qs[QROWS][64];   // 30.5 KB
  __shared__ float Ws[LENFT][64];   // 18.4 KB
  __shared__ float Rs[TTILE][68];   // 13.1 KB (pad 68: float4-aligned rows)

  int bid  = blockIdx.x;
  int xcd  = bid & 7, pos = bid >> 3;
  const int q = NWG / 8, r = NWG % 8;              // 93, 6
  int wgid = ((xcd < r) ? xcd * (q + 1) : r * (q + 1) + (xcd - r) * q) + pos;
  int tile  = wgid % NTILES_T;      // consecutive wgid -> consecutive tiles
  int split = wgid / NTILES_T;
  int t0    = tile * TTILE;
  int tid   = threadIdx.x;
  int wid   = tid >> 6, lane = tid & 63;

  int nn = tid & 63;                // conv: cell within subtile
  int tc = wid * 12;                // conv: 12 consecutive t-rows
  int oe = tid & 31;                // einsum: outlet
  int te = (tid >> 5) * 6;          // einsum: 6 consecutive t-rows

  auto stage = [&](int sub) {
    int n0 = (split * SUBS + sub) * 64;
    for (int rr = wid; rr < QROWS; rr += 4) {
      int t = t0 - 71 + rr;
      if (t >= 0)
        __builtin_amdgcn_global_load_lds(
            (gas_void*)(Q + (size_t)t * NG + n0 + lane),
            (las_void*)(&Qs[rr][0]), 4, 0, 0);
      else
        Qs[rr][lane] = 0.0f;
    }
    for (int k = wid; k < LENFT; k += 4)
      __builtin_amdgcn_global_load_lds(
          (gas_void*)(W + (size_t)k * NG + n0 + lane),
          (las_void*)(&Ws[k][0]), 4, 0, 0);
  };

  float acc_out[6] = {0.f, 0.f, 0.f, 0.f, 0.f, 0.f};

  stage(0);
  for (int sub = 0; sub < SUBS; sub++) {
    int n0 = (split * SUBS + sub) * 64;

    float4 Greg[16];
    #pragma unroll
    for (int g4 = 0; g4 < 16; g4++) {
      float4 tv = *reinterpret_cast<const float4*>(&topo[oe * NG + n0 + g4 * 4]);
      float4 av = *reinterpret_cast<const float4*>(&areas[n0 + g4 * 4]);
      Greg[g4] = make_float4(tv.x * av.x, tv.y * av.y, tv.z * av.z, tv.w * av.w);
    }

    __syncthreads();   // staging(sub) complete

    float acc[12];
    float qwin[12];
    #pragma unroll
    for (int i = 0; i < 12; i++) { acc[i] = 0.0f; qwin[i] = Qs[tc + i][nn]; }
    #pragma unroll
    for (int kk = 0; kk < LENFT; kk++) {
      float w = Ws[71 - kk][nn];
      #pragma unroll
      for (int i = 0; i < 12; i++) acc[i] += w * qwin[i];
      #pragma unroll
      for (int i = 0; i < 11; i++) qwin[i] = qwin[i + 1];
      if (kk < 71) qwin[11] = Qs[tc + 12 + kk][nn];
    }
    #pragma unroll
    for (int i = 0; i < 12; i++) Rs[tc + i][nn] = acc[i];
    __syncthreads();   // Rs visible; Qs/Ws reads done

    if (sub + 1 < SUBS) stage(sub + 1);   // overlaps with einsum below

    #pragma unroll
    for (int g4 = 0; g4 < 16; g4++) {
      float4 g = Greg[g4];
      #pragma unroll
      for (int p = 0; p < 6; p++) {
        float4 rv = *reinterpret_cast<const float4*>(&Rs[te + p][g4 * 4]);
        acc_out[p] += rv.x * g.x + rv.y * g.y + rv.z * g.z + rv.w * g.w;
      }
    }
  }

  #pragma unroll
  for (int p = 0; p < 6; p++) {
    int tg = t0 + te + p;           // always < 1440 (30*48 exact)
    Par[(split * TS + tg) * NOUT + oe] = acc_out[p];
  }
}

// ---------------------------------------------------------------------------
// Kernel 4: reduce partials over the 25 n-splits
// ---------------------------------------------------------------------------
__global__ __launch_bounds__(256) void reduce_kernel(
    const float* __restrict__ Par, float* __restrict__ out)
{
  int i = blockIdx.x * 256 + threadIdx.x;
  if (i < TS * NOUT) {
    float s = 0.0f;
    #pragma unroll
    for (int sp = 0; sp < NSPLIT; sp++) s += Par[sp * (TS * NOUT) + i];
    out[i] = s;
  }
}

// ---------------------------------------------------------------------------
extern "C" void kernel_launch(void* const* d_in, const int* in_sizes, int n_in,
                              void* d_out, int out_size, void* d_ws, size_t ws_size,
                              hipStream_t stream)
{
  const float* x_phy  = (const float*)d_in[0];
  const float* ac_all = (const float*)d_in[1];
  // d_in[2] = elev_all (unused by reference)
  const float* topo   = (const float*)d_in[3];
  const float* areas  = (const float*)d_in[4];
  const float* p1     = (const float*)d_in[5];
  const float* p2     = (const float*)d_in[6];
  float* out = (float*)d_out;

  char* ws = (char*)d_ws;
  float* Q   = (float*)(ws);                                  // 46,080,000 B
  float* W   = (float*)(ws + 46080000);                       //  2,304,000 B
  float* Cst = (float*)(ws + 46080000 + 2304000);             //    512,000 B
  float* Par = (float*)(ws + 46080000 + 2304000 + 512000);    //  4,608,000 B

  hipLaunchKernelGGL(precompute_kernel, dim3(32), dim3(256), 0, stream,
                     p1, p2, ac_all, Cst, W);
  hipLaunchKernelGGL(scan_kernel, dim3((NHALF + 63) / 64), dim3(64), 0, stream,
                     x_phy, Cst, Q);
  hipLaunchKernelGGL(route_kernel, dim3(NWG), dim3(256), 0, stream,
                     Q, W, topo, areas, Par);
  hipLaunchKernelGGL(reduce_kernel, dim3((TS * NOUT + 255) / 256), dim3(256), 0, stream,
                     Par, out);
}

// Round 14
// 296.567 us; speedup vs baseline: 1.6359x; 1.6359x over previous
//
#include <hip/hip_runtime.h>

#define NG 8000
#define NG3 24000
#define TS 1440
#define NOUT 32
#define LENFT 72
#define DTC (1.0f/24.0f)
#define NEARZEROC 1e-5f

// gfx950 hardware transcendentals (base-2). Pure ops -> non-volatile asm (CSE ok).
__device__ __forceinline__ float fexp2(float x) {
  float r; asm("v_exp_f32 %0, %1" : "=v"(r) : "v"(x)); return r;
}
__device__ __forceinline__ float flog2(float x) {
  float r; asm("v_log_f32 %0, %1" : "=v"(r) : "v"(x)); return r;
}

typedef const void __attribute__((address_space(1))) gas_void;
typedef void __attribute__((address_space(3)))       las_void;

// ---------------------------------------------------------------------------
// Kernel 1: per-cell constants + normalized routing weights
// ---------------------------------------------------------------------------
__global__ __launch_bounds__(256) void precompute_kernel(
    const float* __restrict__ p1, const float* __restrict__ p2,
    const float* __restrict__ ac_all,
    float* __restrict__ Cst,   // 16 * NG floats (SoA)
    float* __restrict__ W)     // LENFT * NG floats (k-major)
{
  int n = blockIdx.x * 256 + threadIdx.x;
  if (n >= NG) return;
  const float* r = p1 + n * 19;
  float BETA   = 1.0f   + r[0]  * 5.0f;
  float FC     = 50.0f  + r[1]  * 950.0f;
  float K0     = 0.05f  + r[2]  * 0.85f;
  float K1     = 0.01f  + r[3]  * 0.49f;
  float K2     = 0.001f + r[4]  * 0.199f;
  float LP     = 0.2f   + r[5]  * 0.8f;
  float PERC   =          r[6]  * 10.0f;
  float UZL    =          r[7]  * 100.0f;
  float TT     = -2.5f  + r[8]  * 5.0f;
  float CFMAX  = 0.5f   + r[9]  * 9.5f;
  float CFR    =          r[10] * 0.1f;
  float CWH    =          r[11] * 0.2f;
  float BETAET = 0.3f   + r[12] * 4.7f;
  float Cpar   =          r[13];
  float RT     =          r[14] * 20.0f;
  float AC     =          r[15] * 2500.0f;
  float F0     = 120.0f + r[16] * 2760.0f;
  float FMIN   =          r[17];
  float ALPHA  = 0.5f   + r[18] * 4.5f;

  float ac  = ac_all[n];
  float fmx = DTC * F0 * (FMIN + (1.0f - FMIN) * expf(-powf(ac / (AC + 1.0f), 1.0f / ALPHA)));

  Cst[ 0*NG+n] = TT;            Cst[ 1*NG+n] = CFMAX * DTC;
  Cst[ 2*NG+n] = CFR*CFMAX*DTC; Cst[ 3*NG+n] = CWH;
  Cst[ 4*NG+n] = fmx;           Cst[ 5*NG+n] = 1.0f / FC;
  Cst[ 6*NG+n] = BETA;          Cst[ 7*NG+n] = FC;
  Cst[ 8*NG+n] = Cpar;          Cst[ 9*NG+n] = 1.0f / (LP * FC);
  Cst[10*NG+n] = BETAET;        Cst[11*NG+n] = PERC * DTC;
  Cst[12*NG+n] = K0 * DTC;      Cst[13*NG+n] = UZL;
  Cst[14*NG+n] = K1 * DTC;      Cst[15*NG+n] = K2 * DTC;

  // routing weights (gamma kernel), normalized
  float a   = fmaxf(p2[n*3+0] * 5.0f,  0.01f);
  float b   = fmaxf(p2[n*3+1] * 12.0f, 0.01f);
  float lag = p2[n*3+2] * 48.0f + RT;
  float am1 = a - 1.0f, invb = 1.0f / b;
  float sum = 0.0f;
  for (int k = 0; k < LENFT; k++) {
    float s  = (k + 0.5f) - lag;
    float sm = fmaxf(s, 1e-6f);
    float wv = (s > 0.0f) ? expf(am1 * logf(sm) - sm * invb) : 0.0f;
    sum += wv;
  }
  float inv = 1.0f / (sum + 1e-8f);
  for (int k = 0; k < LENFT; k++) {
    float s  = (k + 0.5f) - lag;
    float sm = fmaxf(s, 1e-6f);
    float wv = (s > 0.0f) ? expf(am1 * logf(sm) - sm * invb) : 0.0f;
    W[k*NG + n] = wv * inv;
  }
}

// ---------------------------------------------------------------------------
// Kernel 2: sequential HBV scan. Proven skeleton (r11: 238 us, VGPR 48):
// 125 blocks x 64 thr, 8-deep float3 register double-buffer. This round:
// (a) exact algebraic trims — fused melt/refr med3, cap min dropped, et min
//     folded into eps clamp (validated by r13's passing run);
// (b) uniform-base addressing: (x + t*NG3) + 3n and (Q + t*NG) + n so the
//     per-step base is scalar (SALU) and only the lane offset is vector.
// Failed & abandoned: 512-thr blocks (r7, per-CU BW), ILP-2 sequential (r8),
// async-LDS ring (r9), JIT loads (r10), ILP-2 interleaved (r13, compiler
// won't allocate 2 chains' registers).
// ---------------------------------------------------------------------------
struct HbvConst {
  float TT, CFMAXDT, CFRDT, CWH, FMX, IFC, BETA, FC, C, ILF, BETAET,
        PERCDT, K0DT, UZL, K1DT, K2DT;
};

__device__ __forceinline__ void load_const(const float* __restrict__ Cst,
                                           int n, HbvConst& c) {
  c.TT    =Cst[ 0*NG+n]; c.CFMAXDT=Cst[ 1*NG+n]; c.CFRDT =Cst[ 2*NG+n];
  c.CWH   =Cst[ 3*NG+n]; c.FMX    =Cst[ 4*NG+n]; c.IFC   =Cst[ 5*NG+n];
  c.BETA  =Cst[ 6*NG+n]; c.FC     =Cst[ 7*NG+n]; c.C     =Cst[ 8*NG+n];
  c.ILF   =Cst[ 9*NG+n]; c.BETAET =Cst[10*NG+n]; c.PERCDT=Cst[11*NG+n];
  c.K0DT  =Cst[12*NG+n]; c.UZL    =Cst[13*NG+n]; c.K1DT  =Cst[14*NG+n];
  c.K2DT  =Cst[15*NG+n];
}

__device__ __forceinline__ float hbv_step(float P, float Tm, float PET,
    const HbvConst& c, float& SP, float& MW, float& SM, float& SUZ, float& SLZ)
{
  bool  w    = Tm >= c.TT;
  float dT   = Tm - c.TT;
  float rain = w ? P : 0.0f;
  SP += P - rain;
  // fused melt/refr (exact): dT>=0 -> med3 = min(CFMAXDT*dT, SP) = melt;
  // dT<0 -> med3 = max(CFRDT*dT, -MW) = -refr.
  float k  = w ? c.CFMAXDT : c.CFRDT;
  float tr = __builtin_amdgcn_fmed3f(k * dT, -MW, SP);
  MW += tr; SP -= tr;
  float tosoil = fmaxf(MW - c.CWH * SP, 0.0f);
  MW -= tosoil;
  float win   = rain + tosoil;
  float infil = fminf(win, c.FMX);
  float qie   = win - infil;
  float sw    = fminf(fexp2(c.BETA * flog2(SM * c.IFC)), 1.0f);
  float rech  = infil * sw;
  SM += infil - rech;
  float excess = fmaxf(SM - c.FC, 0.0f);
  SM -= excess;
  // cap: outer min(SLZ,.) dead since C*u <= 1
  float u   = fmaxf(1.0f - SM * c.IFC, 0.0f);
  float cap = c.C * SLZ * u;
  SM += cap; SLZ -= cap;
  float ef = fminf(fexp2(c.BETAET * flog2(SM * c.ILF)), 1.0f);
  // et min folded into the eps clamp (exact)
  SM = fmaxf(SM - PET * ef, NEARZEROC);
  SUZ += rech + excess;
  float perc = fminf(SUZ, c.PERCDT);
  SUZ -= perc;
  float q0 = c.K0DT * fmaxf(SUZ - c.UZL, 0.0f);
  SUZ -= q0;
  float q1 = c.K1DT * SUZ;
  SUZ -= q1;
  SLZ += perc;
  float q2 = c.K2DT * SLZ;
  SLZ -= q2;
  return qie + q0 + q1 + q2;
}

// loads with uniform (scalar) base per step + per-lane offset 3n
#define LOADU8(A, T0)                                                         \
  { _Pragma("unroll")                                                         \
    for (int i_ = 0; i_ < 8; i_++) {                                          \
      const float* b_ = x + (size_t)((T0) + i_) * NG3;                        \
      A[i_] = *reinterpret_cast<const float3*>(b_ + 3 * n);                   \
    } }

__global__ __launch_bounds__(64, 1) void scan_kernel(
    const float* __restrict__ x, const float* __restrict__ Cst,
    float* __restrict__ Q)
{
  int n = blockIdx.x * 64 + threadIdx.x;      // NG = 125*64 exact
  HbvConst c; load_const(Cst, n, c);
  float SP=1e-3f, MW=1e-3f, SM=1e-3f, SUZ=1e-3f, SLZ=1e-3f;

  float3 bufA[8], bufB[8];
  LOADU8(bufA, 0);
  for (int tb = 0; tb < TS; tb += 16) {
    LOADU8(bufB, tb + 8);                     // prefetch next 8 steps
    #pragma unroll
    for (int i = 0; i < 8; i++) {
      float* qb = Q + (size_t)(tb + i) * NG;  // uniform base, lane offset n
      qb[n] = hbv_step(bufA[i].x, bufA[i].y, bufA[i].z, c, SP, MW, SM, SUZ, SLZ);
    }
    if (tb + 16 < TS) LOADU8(bufA, tb + 16);
    #pragma unroll
    for (int i = 0; i < 8; i++) {
      float* qb = Q + (size_t)(tb + 8 + i) * NG;
      qb[n] = hbv_step(bufB[i].x, bufB[i].y, bufB[i].z, c, SP, MW, SM, SUZ, SLZ);
    }
  }
}

// ---------------------------------------------------------------------------
// Kernel 3: fused routing FIR (72 taps) + partial einsum — UNCHANGED (r12).
// gll staging, async stage(sub+1) under einsum, bijective XCD chunk swizzle.
// ---------------------------------------------------------------------------
#define TTILE 48
#define NTILES_T 30          // 1440 / 48
#define NSPLIT 25
#define SUBS 5               // subtiles per split (25*5*64 = 8000)
#define QROWS (TTILE + 71)   // 119
#define NWG (NTILES_T * NSPLIT)  // 750

__global__ __launch_bounds__(256, 2) void route_kernel(
    const float* __restrict__ Q, const float* __restrict__ W,
    const float* __restrict__ topo, const float* __restrict__ areas,
    float* __restrict__ Par)   // [NSPLIT][TS][NOUT]
{
  __shared__ float Qs[QROWS][64];   // 30.5 KB
  __shared__ float Ws[LENFT][64];   // 18.4 KB
  __shared__ float Rs[TTILE][68];   // 13.1 KB (pad 68: float4-aligned rows)

  int bid  = blockIdx.x;
  int xcd  = bid & 7, pos = bid >> 3;
  const int q = NWG / 8, r = NWG % 8;              // 93, 6
  int wgid = ((xcd < r) ? xcd * (q + 1) : r * (q + 1) + (xcd - r) * q) + pos;
  int tile  = wgid % NTILES_T;      // consecutive wgid -> consecutive tiles
  int split = wgid / NTILES_T;
  int t0    = tile * TTILE;
  int tid   = threadIdx.x;
  int wid   = tid >> 6, lane = tid & 63;

  int nn = tid & 63;                // conv: cell within subtile
  int tc = wid * 12;                // conv: 12 consecutive t-rows
  int oe = tid & 31;                // einsum: outlet
  int te = (tid >> 5) * 6;          // einsum: 6 consecutive t-rows

  auto stage = [&](int sub) {
    int n0 = (split * SUBS + sub) * 64;
    for (int rr = wid; rr < QROWS; rr += 4) {
      int t = t0 - 71 + rr;
      if (t >= 0)
        __builtin_amdgcn_global_load_lds(
            (gas_void*)(Q + (size_t)t * NG + n0 + lane),
            (las_void*)(&Qs[rr][0]), 4, 0, 0);
      else
        Qs[rr][lane] = 0.0f;
    }
    for (int k = wid; k < LENFT; k += 4)
      __builtin_amdgcn_global_load_lds(
          (gas_void*)(W + (size_t)k * NG + n0 + lane),
          (las_void*)(&Ws[k][0]), 4, 0, 0);
  };

  float acc_out[6] = {0.f, 0.f, 0.f, 0.f, 0.f, 0.f};

  stage(0);
  for (int sub = 0; sub < SUBS; sub++) {
    int n0 = (split * SUBS + sub) * 64;

    float4 Greg[16];
    #pragma unroll
    for (int g4 = 0; g4 < 16; g4++) {
      float4 tv = *reinterpret_cast<const float4*>(&topo[oe * NG + n0 + g4 * 4]);
      float4 av = *reinterpret_cast<const float4*>(&areas[n0 + g4 * 4]);
      Greg[g4] = make_float4(tv.x * av.x, tv.y * av.y, tv.z * av.z, tv.w * av.w);
    }

    __syncthreads();   // staging(sub) complete

    float acc[12];
    float qwin[12];
    #pragma unroll
    for (int i = 0; i < 12; i++) { acc[i] = 0.0f; qwin[i] = Qs[tc + i][nn]; }
    #pragma unroll
    for (int kk = 0; kk < LENFT; kk++) {
      float w = Ws[71 - kk][nn];
      #pragma unroll
      for (int i = 0; i < 12; i++) acc[i] += w * qwin[i];
      #pragma unroll
      for (int i = 0; i < 11; i++) qwin[i] = qwin[i + 1];
      if (kk < 71) qwin[11] = Qs[tc + 12 + kk][nn];
    }
    #pragma unroll
    for (int i = 0; i < 12; i++) Rs[tc + i][nn] = acc[i];
    __syncthreads();   // Rs visible; Qs/Ws reads done

    if (sub + 1 < SUBS) stage(sub + 1);   // overlaps with einsum below

    #pragma unroll
    for (int g4 = 0; g4 < 16; g4++) {
      float4 g = Greg[g4];
      #pragma unroll
      for (int p = 0; p < 6; p++) {
        float4 rv = *reinterpret_cast<const float4*>(&Rs[te + p][g4 * 4]);
        acc_out[p] += rv.x * g.x + rv.y * g.y + rv.z * g.z + rv.w * g.w;
      }
    }
  }

  #pragma unroll
  for (int p = 0; p < 6; p++) {
    int tg = t0 + te + p;           // always < 1440 (30*48 exact)
    Par[(split * TS + tg) * NOUT + oe] = acc_out[p];
  }
}

// ---------------------------------------------------------------------------
// Kernel 4: reduce partials over the 25 n-splits
// ---------------------------------------------------------------------------
__global__ __launch_bounds__(256) void reduce_kernel(
    const float* __restrict__ Par, float* __restrict__ out)
{
  int i = blockIdx.x * 256 + threadIdx.x;
  if (i < TS * NOUT) {
    float s = 0.0f;
    #pragma unroll
    for (int sp = 0; sp < NSPLIT; sp++) s += Par[sp * (TS * NOUT) + i];
    out[i] = s;
  }
}

// ---------------------------------------------------------------------------
extern "C" void kernel_launch(void* const* d_in, const int* in_sizes, int n_in,
                              void* d_out, int out_size, void* d_ws, size_t ws_size,
                              hipStream_t stream)
{
  const float* x_phy  = (const float*)d_in[0];
  const float* ac_all = (const float*)d_in[1];
  // d_in[2] = elev_all (unused by reference)
  const float* topo   = (const float*)d_in[3];
  const float* areas  = (const float*)d_in[4];
  const float* p1     = (const float*)d_in[5];
  const float* p2     = (const float*)d_in[6];
  float* out = (float*)d_out;

  char* ws = (char*)d_ws;
  float* Q   = (float*)(ws);                                  // 46,080,000 B
  float* W   = (float*)(ws + 46080000);                       //  2,304,000 B
  float* Cst = (float*)(ws + 46080000 + 2304000);             //    512,000 B
  float* Par = (float*)(ws + 46080000 + 2304000 + 512000);    //  4,608,000 B

  hipLaunchKernelGGL(precompute_kernel, dim3(32), dim3(256), 0, stream,
                     p1, p2, ac_all, Cst, W);
  hipLaunchKernelGGL(scan_kernel, dim3(NG / 64), dim3(64), 0, stream,
                     x_phy, Cst, Q);
  hipLaunchKernelGGL(route_kernel, dim3(NWG), dim3(256), 0, stream,
                     Q, W, topo, areas, Par);
  hipLaunchKernelGGL(reduce_kernel, dim3((TS * NOUT + 255) / 256), dim3(256), 0, stream,
                     Par, out);
}